// Round 8
// baseline (252.337 us; speedup 1.0000x reference)
//
#include <hip/hip_runtime.h>

// Problem constants
constexpr int Bn = 8192;   // batch
constexpr int Dd = 2048;   // dims
constexpr int Kk = 512;    // components
constexpr int Qq = 8;      // factors
constexpr int Nn = Kk * 9; // GEMM N: 8 PinvW cols + 1 g col per component = 4608
constexpr float DLOG2PI = 3763.9722f; // D * log(2*pi)

// GEMM tiling: 256x144 tile, BK=128 fp8 bytes (8 x 16B chunks per row, XOR-swizzled)
constexpr int BM = 256, BN = 144, BK = 128;

// Quantization scales (powers of 2, folded out in the epilogue)
constexpr float SX = 16.f;   // x
constexpr float SW = 64.f;   // W columns (q<8)
constexpr float SG = 16.f;   // g column  (q==8)
constexpr float INV_UW = 1.f / (16.f * 64.f);  // u = cp/1024
constexpr float INV_UG = 1.f / (16.f * 16.f);  // s = cp/256

// Workspace layout (bytes)
constexpr size_t OFF_LDP   = 8192;       // logdetPsi scalar
constexpr size_t OFF_LOGPI = 8448;       // K*4
constexpr size_t OFF_OFFK  = 10752;      // K*4
constexpr size_t OFF_MINV  = 13056;      // K*64*4
constexpr size_t OFF_XPX   = 144384;     // B*4
constexpr size_t OFF_XBF   = 177408;     // x fp8: B*D*1
constexpr size_t OFF_GT    = 33731840;   // G fp8: N*D*1  (Gq[n][d], k-contig rows)
constexpr size_t OFF_LL    = 52606208;   // B*K*4
constexpr size_t OFF_PART  = 69383424;   // 2048*4

typedef float f32x4 __attribute__((ext_vector_type(4)));
typedef int   i32x4v __attribute__((ext_vector_type(4)));
typedef int   i32x8v __attribute__((ext_vector_type(8)));

__device__ inline float softplusf(float x) {
  return fmaxf(x, 0.f) + log1pf(expf(-fabsf(x)));
}
__device__ inline unsigned short f2bf(float x) {
  unsigned int u = __builtin_bit_cast(unsigned int, x);
  u = (u + 0x7fffu + ((u >> 16) & 1u)) >> 16;
  return (unsigned short)u;
}
__device__ inline unsigned int pack2(float a, float b) {
  return (unsigned int)f2bf(a) | ((unsigned int)f2bf(b) << 16);
}
__device__ inline float bf2f(unsigned int u16) {
  unsigned int v = u16 << 16;
  return __builtin_bit_cast(float, v);
}
// single float -> fp8 e4m3 (OCP on gfx950), RNE
__device__ inline unsigned char f2fp8(float x) {
  int v = __builtin_amdgcn_cvt_pk_fp8_f32(x, 0.f, 0, false);
  return (unsigned char)(v & 0xff);
}
// async global->LDS, 16B per lane; LDS dest is wave-uniform base + lane*16
__device__ inline void glds16(const unsigned char* g, char* l) {
  __builtin_amdgcn_global_load_lds(
      (const __attribute__((address_space(1))) unsigned int*)g,
      (__attribute__((address_space(3))) unsigned int*)l, 16, 0, 0);
}
// load one 32B fp8 fragment (k-bytes quad*32..+31) from a 128B swizzled row
__device__ inline i32x8v ld_frag(const char* rowp, int quad, int s8) {
  i32x4v lo = *(const i32x4v*)(rowp + (((2 * quad)     ^ s8) * 16));
  i32x4v hi = *(const i32x4v*)(rowp + (((2 * quad + 1) ^ s8) * 16));
  i32x8v r;
  r[0] = lo[0]; r[1] = lo[1]; r[2] = lo[2]; r[3] = lo[3];
  r[4] = hi[0]; r[5] = hi[1]; r[6] = hi[2]; r[7] = hi[3];
  return r;
}

// ---------------- Fused prep kernel ----------------
// Grid = Kk + Bn + 1 blocks:
//   [0, Kk)        k-work: per-component stats/Cholesky/Minv/offk + Gq fp8 rows
//   [Kk, Kk+Bn)    x-work: one batch row -> fp8 + xT Psi^-1 x
//   Kk+Bn          scalars: logdetPsi + log_softmax(pi)
// All three are independent: psi_inv is recomputed inline (cheap softplus);
// -0.5*logdetPsi + logpi move to the gemm epilogue's sOff load.
__global__ __launch_bounds__(256) void prep_all(
    const float* __restrict__ x, const float* __restrict__ mu,
    const float* __restrict__ dir_raw, const float* __restrict__ scale_rho,
    const float* __restrict__ psi_rho, const float* __restrict__ pi_logits,
    float* __restrict__ logdetPsi, float* __restrict__ logpi,
    float* __restrict__ offk, float* __restrict__ Minv,
    unsigned char* __restrict__ Gq, unsigned char* __restrict__ xq,
    float* __restrict__ xPx) {
  __shared__ unsigned short sDir[Dd * 8];  // bf16 pw*dir, 32 KB (k-work)
  __shared__ float sPwmd[Dd];              // f32 pw*mu, 8 KB (k-work; scratch otherwise)
  __shared__ float redk[4 * 53];
  __shared__ float R[53];
  __shared__ float sAl[8], sAh[8];

  int bid = blockIdx.x;
  int t = threadIdx.x, lane = t & 63, w = t >> 6;

  if (bid >= Kk + Bn) {
    // ---- scalar block: logdetPsi + log_softmax(pi_logits) ----
    float* red = sPwmd;  // 256-float scratch
    float acc = 0.f;
    for (int d = t; d < Dd; d += 256)
      acc += logf(softplusf(psi_rho[d]) + 1e-5f);
    red[t] = acc;
    __syncthreads();
    for (int s = 128; s > 0; s >>= 1) { if (t < s) red[t] += red[t + s]; __syncthreads(); }
    if (t == 0) *logdetPsi = red[0];
    __syncthreads();
    float mx = -3.4e38f;
    for (int i = t; i < Kk; i += 256) mx = fmaxf(mx, pi_logits[i]);
    red[t] = mx;
    __syncthreads();
    for (int s = 128; s > 0; s >>= 1) { if (t < s) red[t] = fmaxf(red[t], red[t + s]); __syncthreads(); }
    mx = red[0];
    __syncthreads();
    float se = 0.f;
    for (int i = t; i < Kk; i += 256) se += expf(pi_logits[i] - mx);
    red[t] = se;
    __syncthreads();
    for (int s = 128; s > 0; s >>= 1) { if (t < s) red[t] += red[t + s]; __syncthreads(); }
    float lse = mx + logf(red[0]);
    for (int i = t; i < Kk; i += 256) logpi[i] = pi_logits[i] - lse;
    return;
  }

  if (bid >= Kk) {
    // ---- x-work: row b -> fp8 (x16) + xT Psi^-1 x ----
    int b = bid - Kk;
    const float4* xr = (const float4*)(x + (size_t)b * Dd);
    const float4* pr = (const float4*)psi_rho;
    float4 v0 = xr[2 * t], v1 = xr[2 * t + 1];
    float4 r0 = pr[2 * t], r1 = pr[2 * t + 1];
    float4 p0, p1;
    p0.x = 1.f / (softplusf(r0.x) + 1e-5f); p0.y = 1.f / (softplusf(r0.y) + 1e-5f);
    p0.z = 1.f / (softplusf(r0.z) + 1e-5f); p0.w = 1.f / (softplusf(r0.w) + 1e-5f);
    p1.x = 1.f / (softplusf(r1.x) + 1e-5f); p1.y = 1.f / (softplusf(r1.y) + 1e-5f);
    p1.z = 1.f / (softplusf(r1.z) + 1e-5f); p1.w = 1.f / (softplusf(r1.w) + 1e-5f);
    float acc = v0.x * v0.x * p0.x + v0.y * v0.y * p0.y + v0.z * v0.z * p0.z + v0.w * v0.w * p0.w
              + v1.x * v1.x * p1.x + v1.y * v1.y * p1.y + v1.z * v1.z * p1.z + v1.w * v1.w * p1.w;
    unsigned int q0 = (unsigned int)__builtin_amdgcn_cvt_pk_fp8_f32(SX * v0.x, SX * v0.y, 0, false);
    q0 = (unsigned int)__builtin_amdgcn_cvt_pk_fp8_f32(SX * v0.z, SX * v0.w, (int)q0, true);
    unsigned int q1 = (unsigned int)__builtin_amdgcn_cvt_pk_fp8_f32(SX * v1.x, SX * v1.y, 0, false);
    q1 = (unsigned int)__builtin_amdgcn_cvt_pk_fp8_f32(SX * v1.z, SX * v1.w, (int)q1, true);
    uint2 o; o.x = q0; o.y = q1;
    *(uint2*)(xq + (size_t)b * Dd + t * 8) = o;
#pragma unroll
    for (int s2 = 32; s2; s2 >>= 1) acc += __shfl_down(acc, s2, 64);
    float* r4 = sPwmd;
    if (lane == 0) r4[w] = acc;
    __syncthreads();
    if (t == 0) xPx[b] = r4[0] + r4[1] + r4[2] + r4[3];
    return;
  }

  // ---- k-work ----
  int k = bid;
  float vals[53];
#pragma unroll
  for (int i = 0; i < 53; i++) vals[i] = 0.f;
  const float4* dirp = (const float4*)(dir_raw + (size_t)k * Dd * Qq);
  for (int d = t; d < Dd; d += 256) {
    float4 da = dirp[d * 2], db = dirp[d * 2 + 1];
    float dir8[8] = {da.x, da.y, da.z, da.w, db.x, db.y, db.z, db.w};
    float pw = 1.f / (softplusf(psi_rho[d]) + 1e-5f);
    float md = mu[(size_t)k * Dd + d];
    int c = 0;
#pragma unroll
    for (int i = 0; i < 8; i++) {
      float dip = dir8[i] * pw;
#pragma unroll
      for (int j = 0; j < 8; j++) {
        if (j < i) continue;
        vals[c] += dip * dir8[j]; c++;
      }
    }
#pragma unroll
    for (int q = 0; q < 8; q++) vals[36 + q] += dir8[q] * dir8[q];
    float mp = md * pw;
#pragma unroll
    for (int q = 0; q < 8; q++) vals[44 + q] += mp * dir8[q];
    vals[52] += md * mp;
    // cache pw*dir as bf16, single b128 store
    uint4 pk;
    pk.x = pack2(pw * dir8[0], pw * dir8[1]);
    pk.y = pack2(pw * dir8[2], pw * dir8[3]);
    pk.z = pack2(pw * dir8[4], pw * dir8[5]);
    pk.w = pack2(pw * dir8[6], pw * dir8[7]);
    *(uint4*)(sDir + d * 8) = pk;
    sPwmd[d] = mp;
  }
#pragma unroll
  for (int v = 0; v < 53; v++) {
    float val = vals[v];
#pragma unroll
    for (int o = 32; o; o >>= 1) val += __shfl_down(val, o, 64);
    if (lane == 0) redk[w * 53 + v] = val;
  }
  __syncthreads();
  if (t < 53) R[t] = redk[t] + redk[53 + t] + redk[106 + t] + redk[159 + t];
  __syncthreads();
  if (t == 0) {
    float Sf[8][8];
    {
      int c2 = 0;
#pragma unroll
      for (int i = 0; i < 8; i++) {
#pragma unroll
        for (int j = 0; j < 8; j++) {
          if (j < i) continue;
          float v = R[c2++]; Sf[i][j] = v; Sf[j][i] = v;
        }
      }
    }
    float alpha[8];
#pragma unroll
    for (int q = 0; q < 8; q++) {
      float nr = fmaxf(sqrtf(R[36 + q]), 1e-5f);
      alpha[q] = softplusf(scale_rho[(size_t)k * 8 + q]) / nr;
    }
    float Mm[8][8];
#pragma unroll
    for (int i = 0; i < 8; i++)
#pragma unroll
      for (int j = 0; j < 8; j++)
        Mm[i][j] = alpha[i] * alpha[j] * Sf[i][j] + (i == j ? 1.f : 0.f);
    float L[8][8], Ld[8];
#pragma unroll
    for (int i = 0; i < 8; i++) {
#pragma unroll
      for (int j = 0; j < 8; j++) {
        if (j > i) continue;
        float s2 = Mm[i][j];
#pragma unroll
        for (int p = 0; p < 8; p++) { if (p < j) s2 -= L[i][p] * L[j][p]; }
        if (i == j) { L[i][i] = sqrtf(s2); Ld[i] = 1.f / L[i][i]; }
        else        L[i][j] = s2 * Ld[j];
      }
    }
    float logdetM = 0.f;
#pragma unroll
    for (int i = 0; i < 8; i++) logdetM += 2.f * logf(L[i][i]);
    float wv[8];
#pragma unroll
    for (int q = 0; q < 8; q++) wv[q] = alpha[q] * R[44 + q];
    float y[8], h[8];
#pragma unroll
    for (int i = 0; i < 8; i++) {
      float s2 = wv[i];
#pragma unroll
      for (int p = 0; p < 8; p++) { if (p < i) s2 -= L[i][p] * y[p]; }
      y[i] = s2 * Ld[i];
    }
#pragma unroll
    for (int i = 7; i >= 0; i--) {
      float s2 = y[i];
#pragma unroll
      for (int p = 0; p < 8; p++) { if (p > i) s2 -= L[p][i] * h[p]; }
      h[i] = s2 * Ld[i];
    }
    float cc = R[52];
#pragma unroll
    for (int q = 0; q < 8; q++) cc -= wv[q] * h[q];
#pragma unroll
    for (int col = 0; col < 8; col++) {
      float yy[8], z[8];
#pragma unroll
      for (int i = 0; i < 8; i++) {
        float s2 = (i == col) ? 1.f : 0.f;
#pragma unroll
        for (int p = 0; p < 8; p++) { if (p < i) s2 -= L[i][p] * yy[p]; }
        yy[i] = s2 * Ld[i];
      }
#pragma unroll
      for (int i = 7; i >= 0; i--) {
        float s2 = yy[i];
#pragma unroll
        for (int p = 0; p < 8; p++) { if (p > i) s2 -= L[p][i] * z[p]; }
        z[i] = s2 * Ld[i];
      }
#pragma unroll
      for (int r2 = 0; r2 < 8; r2++) Minv[(size_t)k * 64 + r2 * 8 + col] = z[r2];
    }
    // NOTE: logdetPsi and logpi are folded into sOff in the gemm epilogue
    offk[k] = -0.5f * (DLOG2PI + logdetM + cc);
#pragma unroll
    for (int q = 0; q < 8; q++) { sAl[q] = alpha[q]; sAh[q] = alpha[q] * h[q]; }
  }
  __syncthreads();
  float al[8], ah[8];
#pragma unroll
  for (int q = 0; q < 8; q++) { al[q] = sAl[q]; ah[q] = sAh[q]; }
  // Pass 2 (LDS only): Gq rows (k*9+q) from b128 reads of sDir
  for (int d = t; d < Dd; d += 256) {
    uint4 pk = *(const uint4*)(sDir + d * 8);
    float pd[8];
    pd[0] = bf2f(pk.x & 0xffffu); pd[1] = bf2f(pk.x >> 16);
    pd[2] = bf2f(pk.y & 0xffffu); pd[3] = bf2f(pk.y >> 16);
    pd[4] = bf2f(pk.z & 0xffffu); pd[5] = bf2f(pk.z >> 16);
    pd[6] = bf2f(pk.w & 0xffffu); pd[7] = bf2f(pk.w >> 16);
    float gs = 0.f;
#pragma unroll
    for (int q = 0; q < 8; q++) {
      Gq[((size_t)(k * 9 + q)) * Dd + d] = f2fp8(SW * al[q] * pd[q]);
      gs += ah[q] * pd[q];
    }
    Gq[((size_t)(k * 9 + 8)) * Dd + d] = f2fp8(SG * (sPwmd[d] - gs));
  }
}

// ---------------- Kernel D: fused MX-fp8 GEMM + ll epilogue ----------------
// BM=256: wave w owns rows w*64..w*64+63 (4 m-frags) x all 9 n-frags.
// acc = 4*9*4 = 144 regs (AGPR side). __launch_bounds__(256,2).
// LDS: As 256x128B=32768 | Bs 144x128B=18432 @32768 (staging end 51200)
//      Cs (union, per-wave private strips) | sMinv @51200 | sOff @55360
__global__ __launch_bounds__(256, 2) void gemm_ll(
    const unsigned char* __restrict__ xq, const unsigned char* __restrict__ Gq,
    const float* __restrict__ Minv, const float* __restrict__ offk,
    const float* __restrict__ logpi, const float* __restrict__ logdetPsi,
    const float* __restrict__ xPx, float* __restrict__ ll) {
  __shared__ char smem[55424];
  float* Cs    = (float*)smem;                           // [4][16][148] f32 (union)
  float* sMinv = (float*)(smem + 51200);                 // [16][65]
  float* sOff  = (float*)(smem + 51200 + 4160);          // [16]

  int t = threadIdx.x, lane = t & 63, w = t >> 6;
  int m0 = blockIdx.y * BM;
  int n0 = blockIdx.x * BN;
  int comp0 = blockIdx.x * 16;

  // load Minv into padded-stride LDS
  for (int i = t; i < 1024; i += 256) {
    int cl = i >> 6, idx = i & 63;
    sMinv[cl * 65 + idx] = Minv[(size_t)comp0 * 64 + i];
  }
  if (t < 16)
    sOff[t] = offk[comp0 + t] + logpi[comp0 + t] - 0.5f * logdetPsi[0];

  f32x4 acc[4][9];
  f32x4 zero = {0.f, 0.f, 0.f, 0.f};
#pragma unroll
  for (int mt = 0; mt < 4; mt++)
#pragma unroll
    for (int nt = 0; nt < 9; nt++) acc[mt][nt] = zero;

  // staging geometry: each 1KB wave-load covers 8 rows x 8 chunks of 16B
  int rr  = lane >> 3;        // row within 8-row group
  int cph = lane & 7;         // physical chunk slot in LDS
  int csw = cph ^ rr;         // swizzled global chunk index
  // fragment-read geometry
  int quad = lane >> 4, r16 = lane & 15;
  int s8 = r16 & 7;

#pragma unroll 1
  for (int k0 = 0; k0 < Dd; k0 += BK) {
    __syncthreads();  // previous iteration's reads done before overwriting LDS
    // A tile: 32 wave-loads; wave w stages its own 64 rows (jj = 8w..8w+7)
#pragma unroll
    for (int j = 0; j < 8; ++j) {
      int jj = w * 8 + j;
      glds16(xq + (size_t)(m0 + jj * 8 + rr) * Dd + k0 + csw * 16,
             smem + jj * 1024);
    }
    // B tile: 18 wave-loads round-robin
    for (int jj = w; jj < 18; jj += 4) {
      glds16(Gq + (size_t)(n0 + jj * 8 + rr) * Dd + k0 + csw * 16,
             smem + 32768 + jj * 1024);
    }
    __syncthreads();  // glds completion drained here
    i32x8v a0 = ld_frag(smem + (w * 64 +      r16) * 128, quad, s8);
    i32x8v a1 = ld_frag(smem + (w * 64 + 16 + r16) * 128, quad, s8);
    i32x8v a2 = ld_frag(smem + (w * 64 + 32 + r16) * 128, quad, s8);
    i32x8v a3 = ld_frag(smem + (w * 64 + 48 + r16) * 128, quad, s8);
#pragma unroll
    for (int nt = 0; nt < 9; ++nt) {
      i32x8v bv = ld_frag(smem + 32768 + (nt * 16 + r16) * 128, quad, s8);
      acc[0][nt] = __builtin_amdgcn_mfma_scale_f32_16x16x128_f8f6f4(
          a0, bv, acc[0][nt], 0, 0, 0, 0x7f7f7f7f, 0, 0x7f7f7f7f);
      acc[1][nt] = __builtin_amdgcn_mfma_scale_f32_16x16x128_f8f6f4(
          a1, bv, acc[1][nt], 0, 0, 0, 0x7f7f7f7f, 0, 0x7f7f7f7f);
      acc[2][nt] = __builtin_amdgcn_mfma_scale_f32_16x16x128_f8f6f4(
          a2, bv, acc[2][nt], 0, 0, 0, 0x7f7f7f7f, 0, 0x7f7f7f7f);
      acc[3][nt] = __builtin_amdgcn_mfma_scale_f32_16x16x128_f8f6f4(
          a3, bv, acc[3][nt], 0, 0, 0, 0x7f7f7f7f, 0, 0x7f7f7f7f);
    }
  }

  // Hoisted Minv upper-triangle (comp = r16, invariant). 0.5 folded into diag.
  float P[36];
  {
    const float* Mi = sMinv + r16 * 65;
    int c = 0;
#pragma unroll
    for (int i2 = 0; i2 < 8; i2++) {
      P[c++] = 0.5f * Mi[i2 * 8 + i2];
#pragma unroll
      for (int j2 = i2 + 1; j2 < 8; j2++) P[c++] = Mi[i2 * 8 + j2];
    }
  }
  float offc = sOff[r16];

  // Epilogue: 4 mt phases; each wave round-trips its 16x144 sub-tile through
  // its PRIVATE Cs strip (no cross-wave sharing) -> one barrier total.
  __syncthreads();
  float* myC = Cs + w * (16 * 148);
#pragma unroll
  for (int mt = 0; mt < 4; ++mt) {
#pragma unroll
    for (int nt = 0; nt < 9; ++nt) {
#pragma unroll
      for (int r = 0; r < 4; r++) {
        myC[(quad * 4 + r) * 148 + nt * 16 + r16] = acc[mt][nt][r];
      }
    }
#pragma unroll
    for (int i = 0; i < 4; i++) {
      int row_l = quad + 4 * i;
      int b = m0 + w * 64 + mt * 16 + row_l;
      const float* cp = myC + row_l * 148 + r16 * 9;
      float u[8];
#pragma unroll
      for (int j = 0; j < 8; j++) u[j] = cp[j] * INV_UW;   // unfold SX*SW
      float s = cp[8] * INV_UG;                            // unfold SX*SG
      float tq = 0.f;
      int c = 0;
#pragma unroll
      for (int i2 = 0; i2 < 8; i2++) {
        float s2 = P[c++] * u[i2];
#pragma unroll
        for (int j2 = i2 + 1; j2 < 8; j2++) s2 += P[c++] * u[j2];
        tq += u[i2] * s2;
      }
      ll[(size_t)b * Kk + comp0 + r16] = offc + s + tq - 0.5f * xPx[b];
    }
  }
}

// ---------------- Kernel E1: logsumexp per row -> block partials ----------------
__global__ __launch_bounds__(256) void lse_rows(
    const float* __restrict__ ll, float* __restrict__ part) {
  int t = threadIdx.x, lane = t & 63, w = t >> 6;
  int b = blockIdx.x * 4 + w;
  const float* row = ll + (size_t)b * Kk;
  float v[8];
  float mx = -3.4e38f;
#pragma unroll
  for (int i = 0; i < 8; i++) { v[i] = row[lane + 64 * i]; mx = fmaxf(mx, v[i]); }
#pragma unroll
  for (int o = 32; o; o >>= 1) mx = fmaxf(mx, __shfl_xor(mx, o, 64));
  float se = 0.f;
#pragma unroll
  for (int i = 0; i < 8; i++) se += expf(v[i] - mx);
#pragma unroll
  for (int o = 32; o; o >>= 1) se += __shfl_xor(se, o, 64);
  __shared__ float r4[4];
  if (lane == 0) r4[w] = -(mx + logf(se));
  __syncthreads();
  if (t == 0) part[blockIdx.x] = r4[0] + r4[1] + r4[2] + r4[3];
}

// ---------------- Kernel E2: final mean ----------------
__global__ __launch_bounds__(256) void final_mean(
    const float* __restrict__ part, float* __restrict__ out) {
  int t = threadIdx.x, lane = t & 63, w = t >> 6;
  float acc = 0.f;
  for (int i = t; i < 2048; i += 256) acc += part[i];
#pragma unroll
  for (int o = 32; o; o >>= 1) acc += __shfl_down(acc, o, 64);
  __shared__ float r4[4];
  if (lane == 0) r4[w] = acc;
  __syncthreads();
  if (t == 0) out[0] = (r4[0] + r4[1] + r4[2] + r4[3]) * (1.0f / 8192.0f);
}

extern "C" void kernel_launch(void* const* d_in, const int* in_sizes, int n_in,
                              void* d_out, int out_size, void* d_ws, size_t ws_size,
                              hipStream_t stream) {
  const float* x         = (const float*)d_in[0];
  const float* mu        = (const float*)d_in[1];
  const float* dir_raw   = (const float*)d_in[2];
  const float* scale_rho = (const float*)d_in[3];
  const float* psi_rho   = (const float*)d_in[4];
  const float* pi_logits = (const float*)d_in[5];
  float* out = (float*)d_out;
  char* ws = (char*)d_ws;

  float* logdetPsi        = (float*)(ws + OFF_LDP);
  float* logpi            = (float*)(ws + OFF_LOGPI);
  float* offk             = (float*)(ws + OFF_OFFK);
  float* Minv             = (float*)(ws + OFF_MINV);
  float* xPx              = (float*)(ws + OFF_XPX);
  unsigned char* xq       = (unsigned char*)(ws + OFF_XBF);
  unsigned char* Gq       = (unsigned char*)(ws + OFF_GT);
  float* ll               = (float*)(ws + OFF_LL);
  float* part             = (float*)(ws + OFF_PART);

  prep_all<<<Kk + Bn + 1, 256, 0, stream>>>(x, mu, dir_raw, scale_rho, psi_rho,
                                            pi_logits, logdetPsi, logpi, offk,
                                            Minv, Gq, xq, xPx);
  dim3 g(Nn / BN, Bn / BM);  // (32, 32)
  gemm_ll<<<g, 256, 0, stream>>>(xq, Gq, Minv, offk, logpi, logdetPsi, xPx, ll);
  lse_rows<<<Bn / 4, 256, 0, stream>>>(ll, part);
  final_mean<<<1, 256, 0, stream>>>(part, out);
}

// Round 9
// 224.937 us; speedup vs baseline: 1.1218x; 1.1218x over previous
//
#include <hip/hip_runtime.h>

// Problem constants
constexpr int Bn = 8192;   // batch
constexpr int Dd = 2048;   // dims
constexpr int Kk = 512;    // components
constexpr int Qq = 8;      // factors
constexpr int Nn = Kk * 9; // GEMM N: 8 PinvW cols + 1 g col per component = 4608
constexpr float DLOG2PI = 3763.9722f; // D * log(2*pi)

// GEMM tiling: 256x144 tile, BK=128 fp8 bytes (8 x 16B chunks per row, XOR-swizzled)
constexpr int BM = 256, BN = 144, BK = 128;

// Quantization scales (powers of 2, folded out in the epilogue)
constexpr float SX = 16.f;   // x
constexpr float SW = 64.f;   // W columns (q<8)
constexpr float SG = 16.f;   // g column  (q==8)
constexpr float INV_UW = 1.f / (16.f * 64.f);  // u = cp/1024
constexpr float INV_UG = 1.f / (16.f * 16.f);  // s = cp/256

// Workspace layout (bytes)
constexpr size_t OFF_PSI   = 0;          // psi_inv: D*4
constexpr size_t OFF_LDP   = 8192;       // logdetPsi scalar
constexpr size_t OFF_LOGPI = 8448;       // K*4
constexpr size_t OFF_OFFK  = 10752;      // K*4
constexpr size_t OFF_MINV  = 13056;      // K*64*4
constexpr size_t OFF_XPX   = 144384;     // B*4
constexpr size_t OFF_XBF   = 177408;     // x fp8: B*D*1
constexpr size_t OFF_GT    = 33731840;   // G fp8: N*D*1  (Gq[n][d], k-contig rows)
constexpr size_t OFF_LL    = 52606208;   // B*K*4
constexpr size_t OFF_PART  = 69383424;   // 2048*4

typedef float f32x4 __attribute__((ext_vector_type(4)));
typedef int   i32x4v __attribute__((ext_vector_type(4)));
typedef int   i32x8v __attribute__((ext_vector_type(8)));

__device__ inline float softplusf(float x) {
  return fmaxf(x, 0.f) + log1pf(expf(-fabsf(x)));
}
__device__ inline unsigned short f2bf(float x) {
  unsigned int u = __builtin_bit_cast(unsigned int, x);
  u = (u + 0x7fffu + ((u >> 16) & 1u)) >> 16;
  return (unsigned short)u;
}
__device__ inline unsigned int pack2(float a, float b) {
  return (unsigned int)f2bf(a) | ((unsigned int)f2bf(b) << 16);
}
__device__ inline float bf2f(unsigned int u16) {
  unsigned int v = u16 << 16;
  return __builtin_bit_cast(float, v);
}
// single float -> fp8 e4m3 (OCP on gfx950), RNE
__device__ inline unsigned char f2fp8(float x) {
  int v = __builtin_amdgcn_cvt_pk_fp8_f32(x, 0.f, 0, false);
  return (unsigned char)(v & 0xff);
}
// async global->LDS, 16B per lane; LDS dest is wave-uniform base + lane*16
__device__ inline void glds16(const unsigned char* g, char* l) {
  __builtin_amdgcn_global_load_lds(
      (const __attribute__((address_space(1))) unsigned int*)g,
      (__attribute__((address_space(3))) unsigned int*)l, 16, 0, 0);
}
// load one 32B fp8 fragment (k-bytes quad*32..+31) from a 128B swizzled row
__device__ inline i32x8v ld_frag(const char* rowp, int quad, int s8) {
  i32x4v lo = *(const i32x4v*)(rowp + (((2 * quad)     ^ s8) * 16));
  i32x4v hi = *(const i32x4v*)(rowp + (((2 * quad + 1) ^ s8) * 16));
  i32x8v r;
  r[0] = lo[0]; r[1] = lo[1]; r[2] = lo[2]; r[3] = lo[3];
  r[4] = hi[0]; r[5] = hi[1]; r[6] = hi[2]; r[7] = hi[3];
  return r;
}

// ---------------- Kernel A: psi_inv, logdetPsi, log_pi (1 block) ----------------
// The ONLY place softplus(psi_rho) is evaluated: 2048 elements once.
// (R8 recomputed it per x-block = 16.8M transcendental evals -> 102us VALU-bound.)
__global__ __launch_bounds__(256) void prep_psi(
    const float* __restrict__ psi_rho, const float* __restrict__ pi_logits,
    float* __restrict__ psi_inv, float* __restrict__ logdetPsi,
    float* __restrict__ logpi) {
  __shared__ float red[256];
  int t = threadIdx.x;
  float acc = 0.f;
  for (int d = t; d < Dd; d += 256) {
    float p = softplusf(psi_rho[d]) + 1e-5f;
    psi_inv[d] = 1.f / p;
    acc += logf(p);
  }
  red[t] = acc;
  __syncthreads();
  for (int s = 128; s > 0; s >>= 1) { if (t < s) red[t] += red[t + s]; __syncthreads(); }
  if (t == 0) *logdetPsi = red[0];
  __syncthreads();
  float mx = -3.4e38f;
  for (int i = t; i < Kk; i += 256) mx = fmaxf(mx, pi_logits[i]);
  red[t] = mx;
  __syncthreads();
  for (int s = 128; s > 0; s >>= 1) { if (t < s) red[t] = fmaxf(red[t], red[t + s]); __syncthreads(); }
  mx = red[0];
  __syncthreads();
  float se = 0.f;
  for (int i = t; i < Kk; i += 256) se += expf(pi_logits[i] - mx);
  red[t] = se;
  __syncthreads();
  for (int s = 128; s > 0; s >>= 1) { if (t < s) red[t] += red[t + s]; __syncthreads(); }
  float lse = mx + logf(red[0]);
  for (int i = t; i < Kk; i += 256) logpi[i] = pi_logits[i] - lse;
}

// ---------------- Fused prep kernel ----------------
// Grid = Kk + Bn blocks (k-work and x-work co-scheduled):
//   [0, Kk)     k-work: per-component stats/Cholesky/Minv/offk + Gq fp8 rows
//   [Kk, Kk+Bn) x-work: one batch row -> fp8 + xT Psi^-1 x
// Both LOAD psi_inv (8 KB, L2-resident) — no transcendental recompute.
__global__ __launch_bounds__(256) void prep_all(
    const float* __restrict__ x, const float* __restrict__ mu,
    const float* __restrict__ dir_raw, const float* __restrict__ scale_rho,
    const float* __restrict__ psi_inv,
    float* __restrict__ offk, float* __restrict__ Minv,
    unsigned char* __restrict__ Gq, unsigned char* __restrict__ xq,
    float* __restrict__ xPx) {
  __shared__ unsigned short sDir[Dd * 8];  // bf16 pw*dir, 32 KB (k-work)
  __shared__ float sPwmd[Dd];              // f32 pw*mu (k-work; scratch for x-work)
  __shared__ float redk[4 * 53];
  __shared__ float R[53];
  __shared__ float sAl[8], sAh[8];

  int bid = blockIdx.x;
  int t = threadIdx.x, lane = t & 63, w = t >> 6;

  if (bid >= Kk) {
    // ---- x-work: row b -> fp8 (x16) + xT Psi^-1 x ----
    int b = bid - Kk;
    const float4* xr = (const float4*)(x + (size_t)b * Dd);
    const float4* pr = (const float4*)psi_inv;
    float4 v0 = xr[2 * t], v1 = xr[2 * t + 1];
    float4 p0 = pr[2 * t], p1 = pr[2 * t + 1];
    float acc = v0.x * v0.x * p0.x + v0.y * v0.y * p0.y + v0.z * v0.z * p0.z + v0.w * v0.w * p0.w
              + v1.x * v1.x * p1.x + v1.y * v1.y * p1.y + v1.z * v1.z * p1.z + v1.w * v1.w * p1.w;
    unsigned int q0 = (unsigned int)__builtin_amdgcn_cvt_pk_fp8_f32(SX * v0.x, SX * v0.y, 0, false);
    q0 = (unsigned int)__builtin_amdgcn_cvt_pk_fp8_f32(SX * v0.z, SX * v0.w, (int)q0, true);
    unsigned int q1 = (unsigned int)__builtin_amdgcn_cvt_pk_fp8_f32(SX * v1.x, SX * v1.y, 0, false);
    q1 = (unsigned int)__builtin_amdgcn_cvt_pk_fp8_f32(SX * v1.z, SX * v1.w, (int)q1, true);
    uint2 o; o.x = q0; o.y = q1;
    *(uint2*)(xq + (size_t)b * Dd + t * 8) = o;
#pragma unroll
    for (int s2 = 32; s2; s2 >>= 1) acc += __shfl_down(acc, s2, 64);
    float* r4 = sPwmd;
    if (lane == 0) r4[w] = acc;
    __syncthreads();
    if (t == 0) xPx[b] = r4[0] + r4[1] + r4[2] + r4[3];
    return;
  }

  // ---- k-work ----
  int k = bid;
  float vals[53];
#pragma unroll
  for (int i = 0; i < 53; i++) vals[i] = 0.f;
  const float4* dirp = (const float4*)(dir_raw + (size_t)k * Dd * Qq);
  for (int d = t; d < Dd; d += 256) {
    float4 da = dirp[d * 2], db = dirp[d * 2 + 1];
    float dir8[8] = {da.x, da.y, da.z, da.w, db.x, db.y, db.z, db.w};
    float pw = psi_inv[d];
    float md = mu[(size_t)k * Dd + d];
    int c = 0;
#pragma unroll
    for (int i = 0; i < 8; i++) {
      float dip = dir8[i] * pw;
#pragma unroll
      for (int j = 0; j < 8; j++) {
        if (j < i) continue;
        vals[c] += dip * dir8[j]; c++;
      }
    }
#pragma unroll
    for (int q = 0; q < 8; q++) vals[36 + q] += dir8[q] * dir8[q];
    float mp = md * pw;
#pragma unroll
    for (int q = 0; q < 8; q++) vals[44 + q] += mp * dir8[q];
    vals[52] += md * mp;
    // cache pw*dir as bf16, single b128 store
    uint4 pk;
    pk.x = pack2(pw * dir8[0], pw * dir8[1]);
    pk.y = pack2(pw * dir8[2], pw * dir8[3]);
    pk.z = pack2(pw * dir8[4], pw * dir8[5]);
    pk.w = pack2(pw * dir8[6], pw * dir8[7]);
    *(uint4*)(sDir + d * 8) = pk;
    sPwmd[d] = mp;
  }
#pragma unroll
  for (int v = 0; v < 53; v++) {
    float val = vals[v];
#pragma unroll
    for (int o = 32; o; o >>= 1) val += __shfl_down(val, o, 64);
    if (lane == 0) redk[w * 53 + v] = val;
  }
  __syncthreads();
  if (t < 53) R[t] = redk[t] + redk[53 + t] + redk[106 + t] + redk[159 + t];
  __syncthreads();
  if (t == 0) {
    float Sf[8][8];
    {
      int c2 = 0;
#pragma unroll
      for (int i = 0; i < 8; i++) {
#pragma unroll
        for (int j = 0; j < 8; j++) {
          if (j < i) continue;
          float v = R[c2++]; Sf[i][j] = v; Sf[j][i] = v;
        }
      }
    }
    float alpha[8];
#pragma unroll
    for (int q = 0; q < 8; q++) {
      float nr = fmaxf(sqrtf(R[36 + q]), 1e-5f);
      alpha[q] = softplusf(scale_rho[(size_t)k * 8 + q]) / nr;
    }
    float Mm[8][8];
#pragma unroll
    for (int i = 0; i < 8; i++)
#pragma unroll
      for (int j = 0; j < 8; j++)
        Mm[i][j] = alpha[i] * alpha[j] * Sf[i][j] + (i == j ? 1.f : 0.f);
    float L[8][8], Ld[8];
#pragma unroll
    for (int i = 0; i < 8; i++) {
#pragma unroll
      for (int j = 0; j < 8; j++) {
        if (j > i) continue;
        float s2 = Mm[i][j];
#pragma unroll
        for (int p = 0; p < 8; p++) { if (p < j) s2 -= L[i][p] * L[j][p]; }
        if (i == j) { L[i][i] = sqrtf(s2); Ld[i] = 1.f / L[i][i]; }
        else        L[i][j] = s2 * Ld[j];
      }
    }
    float logdetM = 0.f;
#pragma unroll
    for (int i = 0; i < 8; i++) logdetM += 2.f * logf(L[i][i]);
    float wv[8];
#pragma unroll
    for (int q = 0; q < 8; q++) wv[q] = alpha[q] * R[44 + q];
    float y[8], h[8];
#pragma unroll
    for (int i = 0; i < 8; i++) {
      float s2 = wv[i];
#pragma unroll
      for (int p = 0; p < 8; p++) { if (p < i) s2 -= L[i][p] * y[p]; }
      y[i] = s2 * Ld[i];
    }
#pragma unroll
    for (int i = 7; i >= 0; i--) {
      float s2 = y[i];
#pragma unroll
      for (int p = 0; p < 8; p++) { if (p > i) s2 -= L[p][i] * h[p]; }
      h[i] = s2 * Ld[i];
    }
    float cc = R[52];
#pragma unroll
    for (int q = 0; q < 8; q++) cc -= wv[q] * h[q];
#pragma unroll
    for (int col = 0; col < 8; col++) {
      float yy[8], z[8];
#pragma unroll
      for (int i = 0; i < 8; i++) {
        float s2 = (i == col) ? 1.f : 0.f;
#pragma unroll
        for (int p = 0; p < 8; p++) { if (p < i) s2 -= L[i][p] * yy[p]; }
        yy[i] = s2 * Ld[i];
      }
#pragma unroll
      for (int i = 7; i >= 0; i--) {
        float s2 = yy[i];
#pragma unroll
        for (int p = 0; p < 8; p++) { if (p > i) s2 -= L[p][i] * z[p]; }
        z[i] = s2 * Ld[i];
      }
#pragma unroll
      for (int r2 = 0; r2 < 8; r2++) Minv[(size_t)k * 64 + r2 * 8 + col] = z[r2];
    }
    // NOTE: logdetPsi and logpi are folded into sOff in the gemm epilogue
    offk[k] = -0.5f * (DLOG2PI + logdetM + cc);
#pragma unroll
    for (int q = 0; q < 8; q++) { sAl[q] = alpha[q]; sAh[q] = alpha[q] * h[q]; }
  }
  __syncthreads();
  float al[8], ah[8];
#pragma unroll
  for (int q = 0; q < 8; q++) { al[q] = sAl[q]; ah[q] = sAh[q]; }
  // Pass 2 (LDS only): Gq rows (k*9+q) from b128 reads of sDir
  for (int d = t; d < Dd; d += 256) {
    uint4 pk = *(const uint4*)(sDir + d * 8);
    float pd[8];
    pd[0] = bf2f(pk.x & 0xffffu); pd[1] = bf2f(pk.x >> 16);
    pd[2] = bf2f(pk.y & 0xffffu); pd[3] = bf2f(pk.y >> 16);
    pd[4] = bf2f(pk.z & 0xffffu); pd[5] = bf2f(pk.z >> 16);
    pd[6] = bf2f(pk.w & 0xffffu); pd[7] = bf2f(pk.w >> 16);
    float gs = 0.f;
#pragma unroll
    for (int q = 0; q < 8; q++) {
      Gq[((size_t)(k * 9 + q)) * Dd + d] = f2fp8(SW * al[q] * pd[q]);
      gs += ah[q] * pd[q];
    }
    Gq[((size_t)(k * 9 + 8)) * Dd + d] = f2fp8(SG * (sPwmd[d] - gs));
  }
}

// ---------------- Kernel D: fused MX-fp8 GEMM + ll epilogue ----------------
// BM=256: wave w owns rows w*64..w*64+63 (4 m-frags) x all 9 n-frags.
// acc = 4*9*4 = 144 regs (AGPR side). __launch_bounds__(256,2).
// LDS: As 256x128B=32768 | Bs 144x128B=18432 @32768 (staging end 51200)
//      Cs (union, per-wave private strips) | sMinv @51200 | sOff @55360
__global__ __launch_bounds__(256, 2) void gemm_ll(
    const unsigned char* __restrict__ xq, const unsigned char* __restrict__ Gq,
    const float* __restrict__ Minv, const float* __restrict__ offk,
    const float* __restrict__ logpi, const float* __restrict__ logdetPsi,
    const float* __restrict__ xPx, float* __restrict__ ll) {
  __shared__ char smem[55424];
  float* Cs    = (float*)smem;                           // [4][16][148] f32 (union)
  float* sMinv = (float*)(smem + 51200);                 // [16][65]
  float* sOff  = (float*)(smem + 51200 + 4160);          // [16]

  int t = threadIdx.x, lane = t & 63, w = t >> 6;
  int m0 = blockIdx.y * BM;
  int n0 = blockIdx.x * BN;
  int comp0 = blockIdx.x * 16;

  // load Minv into padded-stride LDS
  for (int i = t; i < 1024; i += 256) {
    int cl = i >> 6, idx = i & 63;
    sMinv[cl * 65 + idx] = Minv[(size_t)comp0 * 64 + i];
  }
  if (t < 16)
    sOff[t] = offk[comp0 + t] + logpi[comp0 + t] - 0.5f * logdetPsi[0];

  f32x4 acc[4][9];
  f32x4 zero = {0.f, 0.f, 0.f, 0.f};
#pragma unroll
  for (int mt = 0; mt < 4; mt++)
#pragma unroll
    for (int nt = 0; nt < 9; nt++) acc[mt][nt] = zero;

  // staging geometry: each 1KB wave-load covers 8 rows x 8 chunks of 16B
  int rr  = lane >> 3;        // row within 8-row group
  int cph = lane & 7;         // physical chunk slot in LDS
  int csw = cph ^ rr;         // swizzled global chunk index
  // fragment-read geometry
  int quad = lane >> 4, r16 = lane & 15;
  int s8 = r16 & 7;

#pragma unroll 1
  for (int k0 = 0; k0 < Dd; k0 += BK) {
    __syncthreads();  // previous iteration's reads done before overwriting LDS
    // A tile: 32 wave-loads; wave w stages its own 64 rows (jj = 8w..8w+7)
#pragma unroll
    for (int j = 0; j < 8; ++j) {
      int jj = w * 8 + j;
      glds16(xq + (size_t)(m0 + jj * 8 + rr) * Dd + k0 + csw * 16,
             smem + jj * 1024);
    }
    // B tile: 18 wave-loads round-robin
    for (int jj = w; jj < 18; jj += 4) {
      glds16(Gq + (size_t)(n0 + jj * 8 + rr) * Dd + k0 + csw * 16,
             smem + 32768 + jj * 1024);
    }
    __syncthreads();  // glds completion drained here
    i32x8v a0 = ld_frag(smem + (w * 64 +      r16) * 128, quad, s8);
    i32x8v a1 = ld_frag(smem + (w * 64 + 16 + r16) * 128, quad, s8);
    i32x8v a2 = ld_frag(smem + (w * 64 + 32 + r16) * 128, quad, s8);
    i32x8v a3 = ld_frag(smem + (w * 64 + 48 + r16) * 128, quad, s8);
#pragma unroll
    for (int nt = 0; nt < 9; ++nt) {
      i32x8v bv = ld_frag(smem + 32768 + (nt * 16 + r16) * 128, quad, s8);
      acc[0][nt] = __builtin_amdgcn_mfma_scale_f32_16x16x128_f8f6f4(
          a0, bv, acc[0][nt], 0, 0, 0, 0x7f7f7f7f, 0, 0x7f7f7f7f);
      acc[1][nt] = __builtin_amdgcn_mfma_scale_f32_16x16x128_f8f6f4(
          a1, bv, acc[1][nt], 0, 0, 0, 0x7f7f7f7f, 0, 0x7f7f7f7f);
      acc[2][nt] = __builtin_amdgcn_mfma_scale_f32_16x16x128_f8f6f4(
          a2, bv, acc[2][nt], 0, 0, 0, 0x7f7f7f7f, 0, 0x7f7f7f7f);
      acc[3][nt] = __builtin_amdgcn_mfma_scale_f32_16x16x128_f8f6f4(
          a3, bv, acc[3][nt], 0, 0, 0, 0x7f7f7f7f, 0, 0x7f7f7f7f);
    }
  }

  // Hoisted Minv upper-triangle (comp = r16, invariant). 0.5 folded into diag.
  float P[36];
  {
    const float* Mi = sMinv + r16 * 65;
    int c = 0;
#pragma unroll
    for (int i2 = 0; i2 < 8; i2++) {
      P[c++] = 0.5f * Mi[i2 * 8 + i2];
#pragma unroll
      for (int j2 = i2 + 1; j2 < 8; j2++) P[c++] = Mi[i2 * 8 + j2];
    }
  }
  float offc = sOff[r16];

  // Epilogue: 4 mt phases; each wave round-trips its 16x144 sub-tile through
  // its PRIVATE Cs strip (no cross-wave sharing) -> one barrier total.
  __syncthreads();
  float* myC = Cs + w * (16 * 148);
#pragma unroll
  for (int mt = 0; mt < 4; ++mt) {
#pragma unroll
    for (int nt = 0; nt < 9; ++nt) {
#pragma unroll
      for (int r = 0; r < 4; r++) {
        myC[(quad * 4 + r) * 148 + nt * 16 + r16] = acc[mt][nt][r];
      }
    }
#pragma unroll
    for (int i = 0; i < 4; i++) {
      int row_l = quad + 4 * i;
      int b = m0 + w * 64 + mt * 16 + row_l;
      const float* cp = myC + row_l * 148 + r16 * 9;
      float u[8];
#pragma unroll
      for (int j = 0; j < 8; j++) u[j] = cp[j] * INV_UW;   // unfold SX*SW
      float s = cp[8] * INV_UG;                            // unfold SX*SG
      float tq = 0.f;
      int c = 0;
#pragma unroll
      for (int i2 = 0; i2 < 8; i2++) {
        float s2 = P[c++] * u[i2];
#pragma unroll
        for (int j2 = i2 + 1; j2 < 8; j2++) s2 += P[c++] * u[j2];
        tq += u[i2] * s2;
      }
      ll[(size_t)b * Kk + comp0 + r16] = offc + s + tq - 0.5f * xPx[b];
    }
  }
}

// ---------------- Kernel E1: logsumexp per row -> block partials ----------------
__global__ __launch_bounds__(256) void lse_rows(
    const float* __restrict__ ll, float* __restrict__ part) {
  int t = threadIdx.x, lane = t & 63, w = t >> 6;
  int b = blockIdx.x * 4 + w;
  const float* row = ll + (size_t)b * Kk;
  float v[8];
  float mx = -3.4e38f;
#pragma unroll
  for (int i = 0; i < 8; i++) { v[i] = row[lane + 64 * i]; mx = fmaxf(mx, v[i]); }
#pragma unroll
  for (int o = 32; o; o >>= 1) mx = fmaxf(mx, __shfl_xor(mx, o, 64));
  float se = 0.f;
#pragma unroll
  for (int i = 0; i < 8; i++) se += expf(v[i] - mx);
#pragma unroll
  for (int o = 32; o; o >>= 1) se += __shfl_xor(se, o, 64);
  __shared__ float r4[4];
  if (lane == 0) r4[w] = -(mx + logf(se));
  __syncthreads();
  if (t == 0) part[blockIdx.x] = r4[0] + r4[1] + r4[2] + r4[3];
}

// ---------------- Kernel E2: final mean ----------------
__global__ __launch_bounds__(256) void final_mean(
    const float* __restrict__ part, float* __restrict__ out) {
  int t = threadIdx.x, lane = t & 63, w = t >> 6;
  float acc = 0.f;
  for (int i = t; i < 2048; i += 256) acc += part[i];
#pragma unroll
  for (int o = 32; o; o >>= 1) acc += __shfl_down(acc, o, 64);
  __shared__ float r4[4];
  if (lane == 0) r4[w] = acc;
  __syncthreads();
  if (t == 0) out[0] = (r4[0] + r4[1] + r4[2] + r4[3]) * (1.0f / 8192.0f);
}

extern "C" void kernel_launch(void* const* d_in, const int* in_sizes, int n_in,
                              void* d_out, int out_size, void* d_ws, size_t ws_size,
                              hipStream_t stream) {
  const float* x         = (const float*)d_in[0];
  const float* mu        = (const float*)d_in[1];
  const float* dir_raw   = (const float*)d_in[2];
  const float* scale_rho = (const float*)d_in[3];
  const float* psi_rho   = (const float*)d_in[4];
  const float* pi_logits = (const float*)d_in[5];
  float* out = (float*)d_out;
  char* ws = (char*)d_ws;

  float* psi_inv          = (float*)(ws + OFF_PSI);
  float* logdetPsi        = (float*)(ws + OFF_LDP);
  float* logpi            = (float*)(ws + OFF_LOGPI);
  float* offk             = (float*)(ws + OFF_OFFK);
  float* Minv             = (float*)(ws + OFF_MINV);
  float* xPx              = (float*)(ws + OFF_XPX);
  unsigned char* xq       = (unsigned char*)(ws + OFF_XBF);
  unsigned char* Gq       = (unsigned char*)(ws + OFF_GT);
  float* ll               = (float*)(ws + OFF_LL);
  float* part             = (float*)(ws + OFF_PART);

  prep_psi<<<1, 256, 0, stream>>>(psi_rho, pi_logits, psi_inv, logdetPsi, logpi);
  prep_all<<<Kk + Bn, 256, 0, stream>>>(x, mu, dir_raw, scale_rho, psi_inv,
                                        offk, Minv, Gq, xq, xPx);
  dim3 g(Nn / BN, Bn / BM);  // (32, 32)
  gemm_ll<<<g, 256, 0, stream>>>(xq, Gq, Minv, offk, logpi, logdetPsi, xPx, ll);
  lse_rows<<<Bn / 4, 256, 0, stream>>>(ll, part);
  final_mean<<<1, 256, 0, stream>>>(part, out);
}